// Round 1
// baseline (1758.479 us; speedup 1.0000x reference)
//
#include <hip/hip_runtime.h>
#include <hip/hip_bf16.h>

typedef __bf16 bf16_t;
typedef bf16_t bf16x8 __attribute__((ext_vector_type(8)));
typedef bf16_t bf16x4v __attribute__((ext_vector_type(4)));
typedef float f32x4 __attribute__((ext_vector_type(4)));

#define EPSV 1e-5f

__global__ void k_zerof(float* p, int cnt) {
  int i = blockIdx.x * 256 + threadIdx.x;
  if (i < cnt) p[i] = 0.f;
}
__global__ void k_zeroi(int* p, int cnt) {
  int i = blockIdx.x * 256 + threadIdx.x;
  if (i < cnt) p[i] = 0;
}

// W1:[L][128][256] -> W1T:[L][256][128] bf16 ; W2:[L][256][128] -> W2T:[L][128][256] bf16
__global__ void k_prep_weights(const float* __restrict__ W1, const float* __restrict__ W2,
                               bf16_t* __restrict__ W1T, bf16_t* __restrict__ W2T, int total) {
  int idx = blockIdx.x * 256 + threadIdx.x;
  if (idx >= total) return;
  int l = idx >> 15, r = idx & 32767;
  int k = r >> 8, c = r & 255;
  W1T[(l << 15) + c * 128 + k] = (bf16_t)W1[idx];
  int k2 = r >> 7, c2 = r & 127;
  W2T[(l << 15) + c2 * 256 + k2] = (bf16_t)W2[idx];
}

// gamma/beta = task_embs @ film_W + film_b ; out layout [4][g][128]: g0,b0,g1,b1
__global__ void k_film(const float* __restrict__ te, const float* __restrict__ Wg,
                       const float* __restrict__ bg, const float* __restrict__ Wb,
                       const float* __restrict__ bb, float* __restrict__ out, int g) {
  __shared__ float T[32][128];
  int r0 = blockIdx.x * 32;
  int c = threadIdx.x;
  #pragma unroll
  for (int j = 0; j < 32; ++j) T[j][c] = te[(size_t)(r0 + j) * 128 + c];
  __syncthreads();
  for (int m = 0; m < 4; ++m) {
    int fl = m >> 1;
    const float* W = ((m & 1) ? Wb : Wg) + fl * 16384;
    const float* B = ((m & 1) ? bb : bg) + fl * 128;
    float acc[32];
    #pragma unroll
    for (int j = 0; j < 32; ++j) acc[j] = 0.f;
    for (int k = 0; k < 128; ++k) {
      float w = W[k * 128 + c];
      #pragma unroll
      for (int j = 0; j < 32; ++j) acc[j] += T[j][k] * w;
    }
    float bias = B[c];
    float* o = out + (size_t)m * g * 128;
    #pragma unroll
    for (int j = 0; j < 32; ++j) o[(size_t)(r0 + j) * 128 + c] = acc[j] + bias;
  }
}

__global__ void k_init_x(const int* __restrict__ xa, const float* __restrict__ teb,
                         const float* __restrict__ emb1, const float* __restrict__ emb2,
                         float* __restrict__ x, int n, int N) {
  int idx = blockIdx.x * 256 + threadIdx.x;
  if (idx >= N * 128) return;
  int row = idx >> 7, ch = idx & 127;
  float v;
  if (row < n) v = emb1[xa[row * 2] * 128 + ch] + emb2[xa[row * 2 + 1] * 128 + ch];
  else v = teb[(size_t)(row - n) * 128 + ch];
  x[idx] = v;
}

__global__ void k_hist(const int* __restrict__ eidx, int* __restrict__ cnt, int E) {
  int i = blockIdx.x * 256 + threadIdx.x;
  if (i < E) atomicAdd(&cnt[eidx[E + i]], 1);
}

__global__ void k_scan1(const int* __restrict__ cnt, int* __restrict__ part,
                        int* __restrict__ bsum, int n) {
  __shared__ int s[256];
  int i = blockIdx.x * 256 + threadIdx.x;
  int v = (i < n) ? cnt[i] : 0;
  s[threadIdx.x] = v;
  for (int off = 1; off < 256; off <<= 1) {
    __syncthreads();
    int t = (threadIdx.x >= off) ? s[threadIdx.x - off] : 0;
    __syncthreads();
    s[threadIdx.x] += t;
  }
  __syncthreads();
  if (i < n) part[i] = s[threadIdx.x] - v;
  if (threadIdx.x == 255) bsum[blockIdx.x] = s[255];
}

__global__ void k_scan2(int* bsum, int nb) {
  __shared__ int s[512];
  int v = ((int)threadIdx.x < nb) ? bsum[threadIdx.x] : 0;
  s[threadIdx.x] = v;
  for (int off = 1; off < 512; off <<= 1) {
    __syncthreads();
    int t = ((int)threadIdx.x >= off) ? s[threadIdx.x - off] : 0;
    __syncthreads();
    s[threadIdx.x] += t;
  }
  __syncthreads();
  if ((int)threadIdx.x < nb) bsum[threadIdx.x] = s[threadIdx.x] - v;
}

__global__ void k_scan3(int* __restrict__ rp, const int* __restrict__ bsum,
                        int* __restrict__ fill, int n, int E) {
  int i = blockIdx.x * 256 + threadIdx.x;
  if (i < n) {
    int v = rp[i] + bsum[i >> 8];
    rp[i] = v;
    fill[i] = v;
  }
  if (i == 0) rp[n] = E;
}

__global__ void k_scatter(const int* __restrict__ eidx, const int* __restrict__ eattr,
                          int* __restrict__ fill, int* __restrict__ pack, int E) {
  int i = blockIdx.x * 256 + threadIdx.x;
  if (i >= E) return;
  int s = eidx[i];
  int d = eidx[E + i];
  int a0 = eattr[2 * i], a1 = eattr[2 * i + 1];
  int p = atomicAdd(&fill[d], 1);
  pack[p] = s | (a0 << 20) | (a1 << 24);
}

// agg = segment_sum(x[src]+emb, dst) + x + self_emb ; virtual edges analytic.
__global__ void k_agg(const float* __restrict__ x, const int* __restrict__ batch,
                      const int* __restrict__ rp, const int* __restrict__ pack,
                      const float* __restrict__ e1, const float* __restrict__ e2,
                      float* __restrict__ agg, int n, int N, int npg) {
  int node = blockIdx.x * 2 + (threadIdx.x >> 7);
  int ch = threadIdx.x & 127;
  if (node >= N) return;
  float e20 = e2[ch];
  float self_e = e1[4 * 128 + ch] + e20;  // e1[4]+e2[0]
  float virt_e = e1[5 * 128 + ch] + e20;  // e1[5]+e2[0]
  float acc;
  if (node < n) {
    int b = batch[node];
    acc = x[(size_t)node * 128 + ch] + x[(size_t)(n + b) * 128 + ch] + self_e + virt_e;
    int beg = rp[node], end = rp[node + 1];
    for (int e = beg; e < end; ++e) {
      int p = pack[e];
      int s = p & 0xFFFFF;
      acc += x[(size_t)s * 128 + ch] + e1[((p >> 20) & 15) * 128 + ch]
           + e2[((p >> 24) & 15) * 128 + ch];
    }
  } else {
    int b = node - n;
    acc = x[(size_t)node * 128 + ch] + self_e + (float)npg * virt_e;
    const float* base = x + (size_t)b * npg * 128;
    #pragma unroll 8
    for (int k = 0; k < npg; ++k) acc += base[(size_t)k * 128 + ch];
  }
  agg[(size_t)node * 128 + ch] = acc;
}

// Fused MLP: y = relu(agg@W1+b1)@W2+b2, optional FiLM on rows<n, + batchnorm stats.
__launch_bounds__(256)
__global__ void k_mlp(const float* __restrict__ agg, const bf16_t* __restrict__ W1T,
                      const bf16_t* __restrict__ W2T, const float* __restrict__ b1,
                      const float* __restrict__ b2, const float* __restrict__ gamma,
                      const float* __restrict__ beta, const int* __restrict__ batch,
                      float* __restrict__ y, float* __restrict__ gstats, int n, int N) {
  __shared__ __align__(16) char lds[16384 + 32768 + 1024];
  char* As = lds;                       // [64][128] bf16, swizzled ^((r&7)<<4)
  char* Hs = lds + 16384;               // [64][256] bf16, swizzled ^((r&15)<<4)
  float* sred = (float*)(lds + 16384 + 32768);  // 256 floats: sum,sumsq
  const int tid = threadIdx.x;
  const int m0 = blockIdx.x * 64;
  sred[tid] = 0.f;
  // stage A tile (f32 -> bf16)
  {
    const float4* src = (const float4*)(agg + (size_t)m0 * 128);
    #pragma unroll
    for (int it = 0; it < 8; ++it) {
      int e4 = it * 256 + tid;
      int r = e4 >> 5, c4 = e4 & 31;
      float4 v;
      if (m0 + r < N) v = src[e4];
      else { v.x = 0.f; v.y = 0.f; v.z = 0.f; v.w = 0.f; }
      bf16x4v h = { (bf16_t)v.x, (bf16_t)v.y, (bf16_t)v.z, (bf16_t)v.w };
      int byte = (r << 8) + (c4 << 3);
      byte ^= (r & 7) << 4;
      *(bf16x4v*)(As + byte) = h;
    }
  }
  __syncthreads();
  const int wave = tid >> 6, lane = tid & 63;
  const int lr = lane & 15, lk = lane >> 4;
  const int arow = wave * 16 + lr;
  // GEMM1: 16 rows x 256 cols per wave, K=128
  f32x4 acc1[16];
  f32x4 zero4 = {0.f, 0.f, 0.f, 0.f};
  #pragma unroll
  for (int cf = 0; cf < 16; ++cf) acc1[cf] = zero4;
  #pragma unroll
  for (int kk = 0; kk < 4; ++kk) {
    int abyte = (arow << 8) + kk * 64 + (lk << 4);
    abyte ^= (arow & 7) << 4;
    bf16x8 a = *(const bf16x8*)(As + abyte);
    #pragma unroll
    for (int cf = 0; cf < 16; ++cf) {
      bf16x8 b = *(const bf16x8*)(W1T + (((cf << 4) + lr) << 7) + kk * 32 + (lk << 3));
      acc1[cf] = __builtin_amdgcn_mfma_f32_16x16x32_bf16(a, b, acc1[cf], 0, 0, 0);
    }
  }
  // bias + relu -> Hs bf16
  #pragma unroll
  for (int cf = 0; cf < 16; ++cf) {
    int col = (cf << 4) + lr;
    float bias = b1[col];
    #pragma unroll
    for (int j = 0; j < 4; ++j) {
      int r = wave * 16 + lk * 4 + j;
      float h = acc1[cf][j] + bias;
      h = h > 0.f ? h : 0.f;
      int byte = (r << 9) + col * 2;
      byte ^= (r & 15) << 4;
      *(bf16_t*)(Hs + byte) = (bf16_t)h;
    }
  }
  __syncthreads();
  // GEMM2: 16 rows x 128 cols per wave, K=256
  f32x4 acc2[8];
  #pragma unroll
  for (int cf = 0; cf < 8; ++cf) acc2[cf] = zero4;
  #pragma unroll
  for (int kk = 0; kk < 8; ++kk) {
    int byte = (arow << 9) + kk * 64 + (lk << 4);
    byte ^= (arow & 15) << 4;
    bf16x8 a = *(const bf16x8*)(Hs + byte);
    #pragma unroll
    for (int cf = 0; cf < 8; ++cf) {
      bf16x8 b = *(const bf16x8*)(W2T + (((cf << 4) + lr) << 8) + kk * 32 + (lk << 3));
      acc2[cf] = __builtin_amdgcn_mfma_f32_16x16x32_bf16(a, b, acc2[cf], 0, 0, 0);
    }
  }
  // epilogue: bias + FiLM + store + stats
  int rows[4]; int gb[4];
  #pragma unroll
  for (int j = 0; j < 4; ++j) {
    rows[j] = m0 + wave * 16 + lk * 4 + j;
    gb[j] = -1;
    if (gamma != nullptr && rows[j] < n) gb[j] = batch[rows[j]];
  }
  #pragma unroll
  for (int cf = 0; cf < 8; ++cf) {
    int col = (cf << 4) + lr;
    float bias = b2[col];
    float s = 0.f, q = 0.f;
    #pragma unroll
    for (int j = 0; j < 4; ++j) {
      if (rows[j] < N) {
        float v = acc2[cf][j] + bias;
        if (gb[j] >= 0)
          v = gamma[(size_t)gb[j] * 128 + col] * v + beta[(size_t)gb[j] * 128 + col];
        y[(size_t)rows[j] * 128 + col] = v;
        s += v; q += v * v;
      }
    }
    s += __shfl_xor(s, 16, 64); s += __shfl_xor(s, 32, 64);
    q += __shfl_xor(q, 16, 64); q += __shfl_xor(q, 32, 64);
    if (lk == 0) { atomicAdd(&sred[col], s); atomicAdd(&sred[128 + col], q); }
  }
  __syncthreads();
  atomicAdd(&gstats[tid], sred[tid]);
}

__global__ void k_finalize(float* stats, const float* __restrict__ bnw,
                           const float* __restrict__ bnb, float invN) {
  int ch = threadIdx.x;
  float mean = stats[ch] * invN;
  float var = stats[128 + ch] * invN - mean * mean;
  var = fmaxf(var, 0.f);
  float inv = rsqrtf(var + EPSV);
  float sc = inv * bnw[ch];
  stats[256 + ch] = sc;
  stats[384 + ch] = bnb[ch] - mean * sc;
}

__global__ void k_norm(const float* __restrict__ yin, const float* __restrict__ stats,
                       float* __restrict__ out, int total4, int relu) {
  int i = blockIdx.x * 256 + threadIdx.x;
  if (i >= total4) return;
  int ch4 = i & 31;
  float4 v = ((const float4*)yin)[i];
  float4 sc = ((const float4*)(stats + 256))[ch4];
  float4 sh = ((const float4*)(stats + 384))[ch4];
  float4 r;
  r.x = v.x * sc.x + sh.x;
  r.y = v.y * sc.y + sh.y;
  r.z = v.z * sc.z + sh.z;
  r.w = v.w * sc.w + sh.w;
  if (relu) {
    r.x = fmaxf(r.x, 0.f); r.y = fmaxf(r.y, 0.f);
    r.z = fmaxf(r.z, 0.f); r.w = fmaxf(r.w, 0.f);
  }
  ((float4*)out)[i] = r;
}

extern "C" void kernel_launch(void* const* d_in, const int* in_sizes, int n_in,
                              void* d_out, int out_size, void* d_ws, size_t ws_size,
                              hipStream_t stream) {
  const int*   x_atoms    = (const int*)d_in[0];
  const int*   edge_index = (const int*)d_in[1];
  const int*   edge_attr  = (const int*)d_in[2];
  const int*   batch      = (const int*)d_in[3];
  const float* task_embs  = (const float*)d_in[6];
  const float* teb        = (const float*)d_in[7];
  const float* emb1       = (const float*)d_in[8];
  const float* emb2       = (const float*)d_in[9];
  const float* edge_e1    = (const float*)d_in[10];
  const float* edge_e2    = (const float*)d_in[11];
  const float* W1         = (const float*)d_in[12];
  const float* b1         = (const float*)d_in[13];
  const float* W2         = (const float*)d_in[14];
  const float* b2         = (const float*)d_in[15];
  const float* bnw        = (const float*)d_in[16];
  const float* bnb        = (const float*)d_in[17];
  const float* fWg        = (const float*)d_in[18];
  const float* fbg        = (const float*)d_in[19];
  const float* fWb        = (const float*)d_in[20];
  const float* fbb        = (const float*)d_in[21];

  const int n   = in_sizes[0] / 2;
  const int E   = in_sizes[1] / 2;
  const int g   = in_sizes[6] / 128;
  const int N   = n + g;
  const int npg = n / g;
  const int L   = in_sizes[12] / 32768;

  char* ws = (char*)d_ws;
  size_t off = 0;
  auto alloc = [&](size_t bytes) { size_t o = off; off += (bytes + 255) & ~(size_t)255; return o; };
  float*  xbuf   = (float*)(ws + alloc((size_t)N * 128 * 4));
  float*  aggbuf = (float*)(ws + alloc((size_t)N * 128 * 4));
  float*  gbuf   = (float*)(ws + alloc((size_t)4 * g * 128 * 4));
  bf16_t* W1Tb   = (bf16_t*)(ws + alloc((size_t)L * 32768 * 2));
  bf16_t* W2Tb   = (bf16_t*)(ws + alloc((size_t)L * 32768 * 2));
  float*  gstats = (float*)(ws + alloc(512 * 4));
  int*    row_ptr= (int*)(ws + alloc((size_t)(n + 1) * 4));
  int*    fill   = (int*)(ws + alloc((size_t)n * 4));
  int*    epack  = (int*)(ws + alloc((size_t)E * 4));
  int*    bsum   = (int*)(ws + alloc(512 * 4));
  (void)ws_size; (void)n_in; (void)out_size;

  // one-time-per-launch precompute
  k_prep_weights<<<(L * 32768 + 255) / 256, 256, 0, stream>>>(W1, W2, W1Tb, W2Tb, L * 32768);
  k_film<<<g / 32, 128, 0, stream>>>(task_embs, fWg, fbg, fWb, fbb, gbuf, g);
  k_init_x<<<(N * 128 + 255) / 256, 256, 0, stream>>>(x_atoms, teb, emb1, emb2, xbuf, n, N);

  // CSR build (by dst) for real edges
  const int nb = (n + 255) / 256;
  k_zeroi<<<nb, 256, 0, stream>>>(fill, n);
  k_hist<<<(E + 255) / 256, 256, 0, stream>>>(edge_index, fill, E);
  k_scan1<<<nb, 256, 0, stream>>>(fill, row_ptr, bsum, n);
  k_scan2<<<1, 512, 0, stream>>>(bsum, nb);
  k_scan3<<<nb, 256, 0, stream>>>(row_ptr, bsum, fill, n, E);
  k_scatter<<<(E + 255) / 256, 256, 0, stream>>>(edge_index, edge_attr, fill, epack, E);

  for (int l = 0; l < 4; ++l) {
    k_zerof<<<1, 256, 0, stream>>>(gstats, 256);
    k_agg<<<(N + 1) / 2, 256, 0, stream>>>(xbuf, batch, row_ptr, epack,
        edge_e1 + (size_t)l * 768, edge_e2 + (size_t)l * 384, aggbuf, n, N, npg);
    const float* gm = nullptr; const float* bt = nullptr;
    if (l == 1) { gm = gbuf;                     bt = gbuf + (size_t)g * 128; }
    if (l == 3) { gm = gbuf + (size_t)2 * g * 128; bt = gbuf + (size_t)3 * g * 128; }
    k_mlp<<<(N + 63) / 64, 256, 0, stream>>>(aggbuf, W1Tb + (size_t)l * 32768,
        W2Tb + (size_t)l * 32768, b1 + l * 256, b2 + l * 128, gm, bt, batch,
        xbuf, gstats, n, N);
    k_finalize<<<1, 128, 0, stream>>>(gstats, bnw + l * 128, bnb + l * 128, 1.0f / (float)N);
    if (l < 3)
      k_norm<<<(N * 32 + 255) / 256, 256, 0, stream>>>(xbuf, gstats, xbuf, N * 32, 1);
    else
      k_norm<<<(n * 32 + 255) / 256, 256, 0, stream>>>(xbuf, gstats, (float*)d_out, n * 32, 0);
  }
}

// Round 2
// 957.189 us; speedup vs baseline: 1.8371x; 1.8371x over previous
//
#include <hip/hip_runtime.h>
#include <hip/hip_bf16.h>

typedef __bf16 bf16_t;
typedef bf16_t bf16x8 __attribute__((ext_vector_type(8)));
typedef bf16_t bf16x2v __attribute__((ext_vector_type(2)));
typedef float f32x4 __attribute__((ext_vector_type(4)));

#define EPSV 1e-5f

__global__ void k_zerof(float* p, int cnt) {
  int i = blockIdx.x * 256 + threadIdx.x;
  if (i < cnt) p[i] = 0.f;
}
__global__ void k_zeroi(int* p, int cnt) {
  int i = blockIdx.x * 256 + threadIdx.x;
  if (i < cnt) p[i] = 0;
}

// W1:[L][128][256] -> W1T:[L][256][128] bf16 ; W2:[L][256][128] -> W2T:[L][128][256] bf16
__global__ void k_prep_weights(const float* __restrict__ W1, const float* __restrict__ W2,
                               bf16_t* __restrict__ W1T, bf16_t* __restrict__ W2T, int total) {
  int idx = blockIdx.x * 256 + threadIdx.x;
  if (idx >= total) return;
  int l = idx >> 15, r = idx & 32767;
  int k = r >> 8, c = r & 255;
  W1T[(l << 15) + c * 128 + k] = (bf16_t)W1[idx];
  int k2 = r >> 7, c2 = r & 127;
  W2T[(l << 15) + c2 * 256 + k2] = (bf16_t)W2[idx];
}

// combined edge emb table: ec[l][i*3+j][128] = e1[l][i] + e2[l][j]
__global__ void k_ecomb(const float* __restrict__ e1, const float* __restrict__ e2,
                        float* __restrict__ ec, int total) {
  int idx = blockIdx.x * 256 + threadIdx.x;
  if (idx >= total) return;
  int ch = idx & 127;
  int t = idx >> 7;
  int comb = t % 18, l = t / 18;
  int i = comb / 3, j = comb % 3;
  ec[idx] = e1[(l * 6 + i) * 128 + ch] + e2[(l * 3 + j) * 128 + ch];
}

// gamma/beta = task_embs @ film_W + film_b ; out layout [4][g][128]: g0,b0,g1,b1
__global__ void k_film(const float* __restrict__ te, const float* __restrict__ Wg,
                       const float* __restrict__ bg, const float* __restrict__ Wb,
                       const float* __restrict__ bb, float* __restrict__ out, int g) {
  __shared__ float T[32][128];
  int r0 = blockIdx.x * 32;
  int c = threadIdx.x;
  #pragma unroll
  for (int j = 0; j < 32; ++j) T[j][c] = te[(size_t)(r0 + j) * 128 + c];
  __syncthreads();
  for (int m = 0; m < 4; ++m) {
    int fl = m >> 1;
    const float* W = ((m & 1) ? Wb : Wg) + fl * 16384;
    const float* B = ((m & 1) ? bb : bg) + fl * 128;
    float acc[32];
    #pragma unroll
    for (int j = 0; j < 32; ++j) acc[j] = 0.f;
    for (int k = 0; k < 128; ++k) {
      float w = W[k * 128 + c];
      #pragma unroll
      for (int j = 0; j < 32; ++j) acc[j] += T[j][k] * w;
    }
    float bias = B[c];
    float* o = out + (size_t)m * g * 128;
    #pragma unroll
    for (int j = 0; j < 32; ++j) o[(size_t)(r0 + j) * 128 + c] = acc[j] + bias;
  }
}

__global__ void k_init_x(const int* __restrict__ xa, const float* __restrict__ teb,
                         const float* __restrict__ emb1, const float* __restrict__ emb2,
                         float* __restrict__ x, int n, int N) {
  int idx = blockIdx.x * 256 + threadIdx.x;
  if (idx >= N * 128) return;
  int row = idx >> 7, ch = idx & 127;
  float v;
  if (row < n) v = emb1[xa[row * 2] * 128 + ch] + emb2[xa[row * 2 + 1] * 128 + ch];
  else v = teb[(size_t)(row - n) * 128 + ch];
  x[idx] = v;
}

__global__ void k_hist(const int* __restrict__ eidx, int* __restrict__ cnt, int E) {
  int i = blockIdx.x * 256 + threadIdx.x;
  if (i < E) atomicAdd(&cnt[eidx[E + i]], 1);
}

__global__ void k_scan1(const int* __restrict__ cnt, int* __restrict__ part,
                        int* __restrict__ bsum, int n) {
  __shared__ int s[256];
  int i = blockIdx.x * 256 + threadIdx.x;
  int v = (i < n) ? cnt[i] : 0;
  s[threadIdx.x] = v;
  for (int off = 1; off < 256; off <<= 1) {
    __syncthreads();
    int t = (threadIdx.x >= off) ? s[threadIdx.x - off] : 0;
    __syncthreads();
    s[threadIdx.x] += t;
  }
  __syncthreads();
  if (i < n) part[i] = s[threadIdx.x] - v;
  if (threadIdx.x == 255) bsum[blockIdx.x] = s[255];
}

__global__ void k_scan2(int* bsum, int nb) {
  __shared__ int s[512];
  int v = ((int)threadIdx.x < nb) ? bsum[threadIdx.x] : 0;
  s[threadIdx.x] = v;
  for (int off = 1; off < 512; off <<= 1) {
    __syncthreads();
    int t = ((int)threadIdx.x >= off) ? s[threadIdx.x - off] : 0;
    __syncthreads();
    s[threadIdx.x] += t;
  }
  __syncthreads();
  if ((int)threadIdx.x < nb) bsum[threadIdx.x] = s[threadIdx.x] - v;
}

__global__ void k_scan3(int* __restrict__ rp, const int* __restrict__ bsum,
                        int* __restrict__ fill, int n, int E) {
  int i = blockIdx.x * 256 + threadIdx.x;
  if (i < n) {
    int v = rp[i] + bsum[i >> 8];
    rp[i] = v;
    fill[i] = v;
  }
  if (i == 0) rp[n] = E;
}

__global__ void k_scatter(const int* __restrict__ eidx, const int* __restrict__ eattr,
                          int* __restrict__ fill, int* __restrict__ pack, int E) {
  int i = blockIdx.x * 256 + threadIdx.x;
  if (i >= E) return;
  int s = eidx[i];
  int d = eidx[E + i];
  int comb = eattr[2 * i] * 3 + eattr[2 * i + 1];
  int p = atomicAdd(&fill[d], 1);
  pack[p] = s | (comb << 20);
}

// agg = segment_sum(norm(x)[src]+emb, dst) + norm(x) + self_emb ; norm fused (scsh),
// virtual edges analytic. Output bf16. One wave per node.
__global__ void k_agg(const float* __restrict__ y, const int* __restrict__ batch,
                      const int* __restrict__ rp, const int* __restrict__ pack,
                      const float* __restrict__ ec, const float* __restrict__ scsh,
                      bf16_t* __restrict__ agg, int n, int N, int npg) {
  int node = blockIdx.x * 4 + (threadIdx.x >> 6);
  if (node >= N) return;
  int c2 = (threadIdx.x & 63) * 2;
  const bool nm = (scsh != nullptr);
  float scx = 1.f, scy = 1.f, shx = 0.f, shy = 0.f;
  if (nm) {
    float2 s = *(const float2*)(scsh + c2); scx = s.x; scy = s.y;
    float2 t = *(const float2*)(scsh + 128 + c2); shx = t.x; shy = t.y;
  }
  #define LDV(row, vx, vy) { \
    float2 _v = *(const float2*)(y + ((size_t)(row) << 7) + c2); \
    if (nm) { _v.x = fmaxf(fmaf(_v.x, scx, shx), 0.f); _v.y = fmaxf(fmaf(_v.y, scy, shy), 0.f); } \
    vx = _v.x; vy = _v.y; }
  float2 self_e = *(const float2*)(ec + 12 * 128 + c2);  // e1[4]+e2[0]
  float2 virt_e = *(const float2*)(ec + 15 * 128 + c2);  // e1[5]+e2[0]
  float ax, ay;
  if (node < n) {
    int b = batch[node];
    float x0, y0, x1, y1;
    LDV(node, x0, y0);
    LDV(n + b, x1, y1);
    ax = x0 + x1 + self_e.x + virt_e.x;
    ay = y0 + y1 + self_e.y + virt_e.y;
    int beg = rp[node], end = rp[node + 1];
    for (int e = beg; e < end; ++e) {
      int p = pack[e];
      float vx, vy;
      LDV(p & 0xFFFFF, vx, vy);
      float2 em = *(const float2*)(ec + ((p >> 20) & 31) * 128 + c2);
      ax += vx + em.x;
      ay += vy + em.y;
    }
  } else {
    int b = node - n;
    float x0, y0;
    LDV(node, x0, y0);
    ax = x0 + self_e.x + (float)npg * virt_e.x;
    ay = y0 + self_e.y + (float)npg * virt_e.y;
    int base = b * npg;
    for (int k = 0; k < npg; ++k) {
      float vx, vy;
      LDV(base + k, vx, vy);
      ax += vx; ay += vy;
    }
  }
  #undef LDV
  bf16x2v o = { (bf16_t)ax, (bf16_t)ay };
  *(bf16x2v*)(agg + ((size_t)node << 7) + c2) = o;
}

// Fused MLP: y = relu(agg@W1+b1)@W2+b2, optional FiLM on rows<n, + batchnorm stats.
// Wave w owns cols [64w,64w+64) of GEMM1 and [32w,32w+32) of GEMM2, all 64 rows.
// All B fragments preloaded to VGPRs; A read directly from bf16 agg.
__launch_bounds__(256, 2)
__global__ void k_mlp(const bf16_t* __restrict__ agg, const bf16_t* __restrict__ W1T,
                      const bf16_t* __restrict__ W2T, const float* __restrict__ b1,
                      const float* __restrict__ b2, const float* __restrict__ gamma,
                      const float* __restrict__ beta, const int* __restrict__ batch,
                      float* __restrict__ y, float* __restrict__ gstats, int n, int N) {
  __shared__ __align__(16) char Hs[32768];   // [64][256] bf16, swizzled ^((r&15)<<4)
  __shared__ float sred[256];
  const int tid = threadIdx.x;
  const int m0 = blockIdx.x * 64;
  const int wave = tid >> 6, lane = tid & 63;
  const int lr = lane & 15, lk = lane >> 4;
  const int w64 = wave * 64, w32 = wave * 32;

  // preload GEMM1 B frags (16 x 16B = 64 VGPR)
  bf16x8 bb1[4][4];
  #pragma unroll
  for (int cf = 0; cf < 4; ++cf)
    #pragma unroll
    for (int kk = 0; kk < 4; ++kk)
      bb1[cf][kk] = *(const bf16x8*)(W1T + ((w64 + cf * 16 + lr) << 7) + kk * 32 + (lk << 3));

  int ar[4];
  #pragma unroll
  for (int rf = 0; rf < 4; ++rf) {
    int r = m0 + rf * 16 + lr;
    ar[rf] = r < N ? r : N - 1;
  }

  f32x4 acc1[4][4];
  f32x4 zero4 = {0.f, 0.f, 0.f, 0.f};
  #pragma unroll
  for (int rf = 0; rf < 4; ++rf)
    #pragma unroll
    for (int cf = 0; cf < 4; ++cf) acc1[rf][cf] = zero4;

  #pragma unroll
  for (int kk = 0; kk < 4; ++kk) {
    bf16x8 a[4];
    #pragma unroll
    for (int rf = 0; rf < 4; ++rf)
      a[rf] = *(const bf16x8*)(agg + ((size_t)ar[rf] << 7) + kk * 32 + (lk << 3));
    #pragma unroll
    for (int rf = 0; rf < 4; ++rf)
      #pragma unroll
      for (int cf = 0; cf < 4; ++cf)
        acc1[rf][cf] = __builtin_amdgcn_mfma_f32_16x16x32_bf16(a[rf], bb1[cf][kk], acc1[rf][cf], 0, 0, 0);
  }

  // preload GEMM2 B frags (overlaps with epilogue1 + barrier)
  bf16x8 bb2[2][8];
  #pragma unroll
  for (int cf = 0; cf < 2; ++cf)
    #pragma unroll
    for (int kk = 0; kk < 8; ++kk)
      bb2[cf][kk] = *(const bf16x8*)(W2T + ((w32 + cf * 16 + lr) << 8) + kk * 32 + (lk << 3));

  // epilogue1: bias + relu -> Hs (bf16, swizzled)
  #pragma unroll
  for (int rf = 0; rf < 4; ++rf)
    #pragma unroll
    for (int cf = 0; cf < 4; ++cf) {
      int col = w64 + cf * 16 + lr;
      float bias = b1[col];
      #pragma unroll
      for (int j = 0; j < 4; ++j) {
        int r = rf * 16 + lk * 4 + j;
        float h = acc1[rf][cf][j] + bias;
        h = h > 0.f ? h : 0.f;
        int byte = (r << 9) + col * 2;
        byte ^= (r & 15) << 4;
        *(bf16_t*)(Hs + byte) = (bf16_t)h;
      }
    }
  __syncthreads();

  f32x4 acc2[4][2];
  #pragma unroll
  for (int rf = 0; rf < 4; ++rf)
    #pragma unroll
    for (int cf = 0; cf < 2; ++cf) acc2[rf][cf] = zero4;

  #pragma unroll
  for (int kk = 0; kk < 8; ++kk) {
    bf16x8 a2[4];
    #pragma unroll
    for (int rf = 0; rf < 4; ++rf) {
      int row = rf * 16 + lr;
      int byte = (row << 9) + kk * 64 + (lk << 4);
      byte ^= (row & 15) << 4;
      a2[rf] = *(const bf16x8*)(Hs + byte);
    }
    #pragma unroll
    for (int rf = 0; rf < 4; ++rf)
      #pragma unroll
      for (int cf = 0; cf < 2; ++cf)
        acc2[rf][cf] = __builtin_amdgcn_mfma_f32_16x16x32_bf16(a2[rf], bb2[cf][kk], acc2[rf][cf], 0, 0, 0);
  }

  int gb[4][4];
  #pragma unroll
  for (int rf = 0; rf < 4; ++rf)
    #pragma unroll
    for (int j = 0; j < 4; ++j) {
      int row = m0 + rf * 16 + lk * 4 + j;
      gb[rf][j] = (gamma != nullptr && row < n) ? batch[row] : -1;
    }

  #pragma unroll
  for (int cf = 0; cf < 2; ++cf) {
    int col = w32 + cf * 16 + lr;
    float bias = b2[col];
    float s = 0.f, q = 0.f;
    #pragma unroll
    for (int rf = 0; rf < 4; ++rf)
      #pragma unroll
      for (int j = 0; j < 4; ++j) {
        int row = m0 + rf * 16 + lk * 4 + j;
        if (row < N) {
          float v = acc2[rf][cf][j] + bias;
          if (gb[rf][j] >= 0)
            v = gamma[(size_t)gb[rf][j] * 128 + col] * v + beta[(size_t)gb[rf][j] * 128 + col];
          y[(size_t)row * 128 + col] = v;
          s += v; q += v * v;
        }
      }
    s += __shfl_xor(s, 16, 64); s += __shfl_xor(s, 32, 64);
    q += __shfl_xor(q, 16, 64); q += __shfl_xor(q, 32, 64);
    if (lane < 16) { sred[col] = s; sred[128 + col] = q; }  // cols wave-partitioned
  }
  __syncthreads();
  atomicAdd(&gstats[((blockIdx.x & 15) << 8) + tid], sred[tid]);
}

// sums 16 partial copies; writes sc at [4096..4223], sh at [4224..4351]
__global__ void k_finalize(float* st, const float* __restrict__ bnw,
                           const float* __restrict__ bnb, float invN) {
  int ch = threadIdx.x;
  float s = 0.f, q = 0.f;
  #pragma unroll
  for (int c = 0; c < 16; ++c) { s += st[c * 256 + ch]; q += st[c * 256 + 128 + ch]; }
  float mean = s * invN;
  float var = fmaxf(q * invN - mean * mean, 0.f);
  float inv = rsqrtf(var + EPSV);
  float sc = inv * bnw[ch];
  st[4096 + ch] = sc;
  st[4224 + ch] = bnb[ch] - mean * sc;
}

// final normalize (no relu) of first n rows -> d_out
__global__ void k_norm(const float* __restrict__ yin, const float* __restrict__ scsh,
                       float* __restrict__ out, int total4) {
  int i = blockIdx.x * 256 + threadIdx.x;
  if (i >= total4) return;
  int ch4 = i & 31;
  float4 v = ((const float4*)yin)[i];
  float4 sc = ((const float4*)scsh)[ch4];
  float4 sh = ((const float4*)(scsh + 128))[ch4];
  float4 r;
  r.x = v.x * sc.x + sh.x;
  r.y = v.y * sc.y + sh.y;
  r.z = v.z * sc.z + sh.z;
  r.w = v.w * sc.w + sh.w;
  ((float4*)out)[i] = r;
}

extern "C" void kernel_launch(void* const* d_in, const int* in_sizes, int n_in,
                              void* d_out, int out_size, void* d_ws, size_t ws_size,
                              hipStream_t stream) {
  const int*   x_atoms    = (const int*)d_in[0];
  const int*   edge_index = (const int*)d_in[1];
  const int*   edge_attr  = (const int*)d_in[2];
  const int*   batch      = (const int*)d_in[3];
  const float* task_embs  = (const float*)d_in[6];
  const float* teb        = (const float*)d_in[7];
  const float* emb1       = (const float*)d_in[8];
  const float* emb2       = (const float*)d_in[9];
  const float* edge_e1    = (const float*)d_in[10];
  const float* edge_e2    = (const float*)d_in[11];
  const float* W1         = (const float*)d_in[12];
  const float* b1         = (const float*)d_in[13];
  const float* W2         = (const float*)d_in[14];
  const float* b2         = (const float*)d_in[15];
  const float* bnw        = (const float*)d_in[16];
  const float* bnb        = (const float*)d_in[17];
  const float* fWg        = (const float*)d_in[18];
  const float* fbg        = (const float*)d_in[19];
  const float* fWb        = (const float*)d_in[20];
  const float* fbb        = (const float*)d_in[21];

  const int n   = in_sizes[0] / 2;
  const int E   = in_sizes[1] / 2;
  const int g   = in_sizes[6] / 128;
  const int N   = n + g;
  const int npg = n / g;
  const int L   = in_sizes[12] / 32768;

  char* ws = (char*)d_ws;
  size_t off = 0;
  auto alloc = [&](size_t bytes) { size_t o = off; off += (bytes + 255) & ~(size_t)255; return o; };
  float*  xbuf   = (float*)(ws + alloc((size_t)N * 128 * 4));
  bf16_t* aggb   = (bf16_t*)(ws + alloc((size_t)N * 128 * 2));
  float*  gbuf   = (float*)(ws + alloc((size_t)4 * g * 128 * 4));
  bf16_t* W1Tb   = (bf16_t*)(ws + alloc((size_t)L * 32768 * 2));
  bf16_t* W2Tb   = (bf16_t*)(ws + alloc((size_t)L * 32768 * 2));
  float*  ecomb  = (float*)(ws + alloc((size_t)L * 18 * 128 * 4));
  float*  gstats = (float*)(ws + alloc((size_t)(4096 + 256) * 4));
  int*    row_ptr= (int*)(ws + alloc((size_t)(n + 1) * 4));
  int*    fill   = (int*)(ws + alloc((size_t)n * 4));
  int*    epack  = (int*)(ws + alloc((size_t)E * 4));
  int*    bsum   = (int*)(ws + alloc(512 * 4));
  (void)ws_size; (void)n_in; (void)out_size;

  // one-time-per-launch precompute
  k_prep_weights<<<(L * 32768 + 255) / 256, 256, 0, stream>>>(W1, W2, W1Tb, W2Tb, L * 32768);
  k_film<<<g / 32, 128, 0, stream>>>(task_embs, fWg, fbg, fWb, fbb, gbuf, g);
  k_init_x<<<(N * 128 + 255) / 256, 256, 0, stream>>>(x_atoms, teb, emb1, emb2, xbuf, n, N);
  k_ecomb<<<(L * 18 * 128 + 255) / 256, 256, 0, stream>>>(edge_e1, edge_e2, ecomb, L * 18 * 128);

  // CSR build (by dst) for real edges
  const int nb = (n + 255) / 256;
  k_zeroi<<<nb, 256, 0, stream>>>(fill, n);
  k_hist<<<(E + 255) / 256, 256, 0, stream>>>(edge_index, fill, E);
  k_scan1<<<nb, 256, 0, stream>>>(fill, row_ptr, bsum, n);
  k_scan2<<<1, 512, 0, stream>>>(bsum, nb);
  k_scan3<<<nb, 256, 0, stream>>>(row_ptr, bsum, fill, n, E);
  k_scatter<<<(E + 255) / 256, 256, 0, stream>>>(edge_index, edge_attr, fill, epack, E);

  for (int l = 0; l < 4; ++l) {
    k_zerof<<<16, 256, 0, stream>>>(gstats, 4096);
    const float* scsh = (l == 0) ? nullptr : (gstats + 4096);
    k_agg<<<(N + 3) / 4, 256, 0, stream>>>(xbuf, batch, row_ptr, epack,
        ecomb + (size_t)l * 18 * 128, scsh, aggb, n, N, npg);
    const float* gm = nullptr; const float* bt = nullptr;
    if (l == 1) { gm = gbuf;                       bt = gbuf + (size_t)g * 128; }
    if (l == 3) { gm = gbuf + (size_t)2 * g * 128; bt = gbuf + (size_t)3 * g * 128; }
    k_mlp<<<(N + 63) / 64, 256, 0, stream>>>(aggb, W1Tb + (size_t)l * 32768,
        W2Tb + (size_t)l * 32768, b1 + l * 256, b2 + l * 128, gm, bt, batch,
        xbuf, gstats, n, N);
    k_finalize<<<1, 128, 0, stream>>>(gstats, bnw + l * 128, bnb + l * 128, 1.0f / (float)N);
  }
  k_norm<<<(n * 32 + 255) / 256, 256, 0, stream>>>(xbuf, gstats + 4096, (float*)d_out, n * 32);
}

// Round 3
// 788.826 us; speedup vs baseline: 2.2292x; 1.2134x over previous
//
#include <hip/hip_runtime.h>
#include <hip/hip_bf16.h>

typedef __bf16 bf16_t;
typedef bf16_t bf16x8 __attribute__((ext_vector_type(8)));
typedef bf16_t bf16x2v __attribute__((ext_vector_type(2)));
typedef float f32x4 __attribute__((ext_vector_type(4)));

#define EPSV 1e-5f

__global__ void k_zerof(float* p, int cnt) {
  int i = blockIdx.x * 256 + threadIdx.x;
  if (i < cnt) p[i] = 0.f;
}
__global__ void k_zeroi(int* p, int cnt) {
  int i = blockIdx.x * 256 + threadIdx.x;
  if (i < cnt) p[i] = 0;
}

// W1:[L][128][256] -> W1T:[L][256][128] bf16 ; W2:[L][256][128] -> W2T:[L][128][256] bf16
__global__ void k_prep_weights(const float* __restrict__ W1, const float* __restrict__ W2,
                               bf16_t* __restrict__ W1T, bf16_t* __restrict__ W2T, int total) {
  int idx = blockIdx.x * 256 + threadIdx.x;
  if (idx >= total) return;
  int l = idx >> 15, r = idx & 32767;
  int k = r >> 8, c = r & 255;
  W1T[(l << 15) + c * 128 + k] = (bf16_t)W1[idx];
  int k2 = r >> 7, c2 = r & 127;
  W2T[(l << 15) + c2 * 256 + k2] = (bf16_t)W2[idx];
}

// film weights -> bf16 transposed [4][c][k]; m: 0=Wg0,1=Wb0,2=Wg1,3=Wb1
__global__ void k_prep_film(const float* __restrict__ Wg, const float* __restrict__ Wb,
                            bf16_t* __restrict__ fWT) {
  int idx = blockIdx.x * 256 + threadIdx.x;
  if (idx >= 4 * 16384) return;
  int m = idx >> 14, r = idx & 16383;
  int c = r >> 7, k = r & 127;
  const float* W = ((m & 1) ? Wb : Wg) + (m >> 1) * 16384;
  fWT[idx] = (bf16_t)W[k * 128 + c];
}

__global__ void k_prep_te(const float* __restrict__ te, bf16_t* __restrict__ teb_out, int total) {
  int idx = blockIdx.x * 256 + threadIdx.x;
  if (idx < total) teb_out[idx] = (bf16_t)te[idx];
}

// combined edge emb table: ec[l][i*3+j][128] = e1[l][i] + e2[l][j]
__global__ void k_ecomb(const float* __restrict__ e1, const float* __restrict__ e2,
                        float* __restrict__ ec, int total) {
  int idx = blockIdx.x * 256 + threadIdx.x;
  if (idx >= total) return;
  int ch = idx & 127;
  int t = idx >> 7;
  int comb = t % 18, l = t / 18;
  int i = comb / 3, j = comb % 3;
  ec[idx] = e1[(l * 6 + i) * 128 + ch] + e2[(l * 3 + j) * 128 + ch];
}

// FiLM GEMM via MFMA: gbuf[m][row][col] = te @ W[m] + b[m]; 4 waves, wave owns 32 cols.
__launch_bounds__(256, 2)
__global__ void k_film(const bf16_t* __restrict__ teb, const bf16_t* __restrict__ fWT,
                       const float* __restrict__ bg, const float* __restrict__ bb,
                       float* __restrict__ gbuf, int g) {
  const int mat = blockIdx.x & 3;
  const int r0 = (blockIdx.x >> 2) * 64;
  const int tid = threadIdx.x;
  const int wave = tid >> 6, lane = tid & 63;
  const int lr = lane & 15, lk = lane >> 4;
  const int w32 = wave * 32;
  const bf16_t* W = fWT + mat * 16384;
  const float* B = ((mat & 1) ? bb : bg) + (mat >> 1) * 128;

  bf16x8 bbf[2][4];
  #pragma unroll
  for (int cf = 0; cf < 2; ++cf)
    #pragma unroll
    for (int kk = 0; kk < 4; ++kk)
      bbf[cf][kk] = *(const bf16x8*)(W + ((w32 + cf * 16 + lr) << 7) + kk * 32 + (lk << 3));

  f32x4 acc[4][2];
  f32x4 zero4 = {0.f, 0.f, 0.f, 0.f};
  #pragma unroll
  for (int rf = 0; rf < 4; ++rf)
    #pragma unroll
    for (int cf = 0; cf < 2; ++cf) acc[rf][cf] = zero4;

  #pragma unroll
  for (int kk = 0; kk < 4; ++kk) {
    bf16x8 a[4];
    #pragma unroll
    for (int rf = 0; rf < 4; ++rf)
      a[rf] = *(const bf16x8*)(teb + ((size_t)(r0 + rf * 16 + lr) << 7) + kk * 32 + (lk << 3));
    #pragma unroll
    for (int rf = 0; rf < 4; ++rf)
      #pragma unroll
      for (int cf = 0; cf < 2; ++cf)
        acc[rf][cf] = __builtin_amdgcn_mfma_f32_16x16x32_bf16(a[rf], bbf[cf][kk], acc[rf][cf], 0, 0, 0);
  }

  float* out = gbuf + (size_t)mat * g * 128;
  #pragma unroll
  for (int cf = 0; cf < 2; ++cf) {
    int col = w32 + cf * 16 + lr;
    float bias = B[col];
    #pragma unroll
    for (int rf = 0; rf < 4; ++rf)
      #pragma unroll
      for (int j = 0; j < 4; ++j) {
        int row = r0 + rf * 16 + lk * 4 + j;
        out[(size_t)row * 128 + col] = acc[rf][cf][j] + bias;
      }
  }
}

__global__ void k_init_x(const int* __restrict__ xa, const float* __restrict__ teb,
                         const float* __restrict__ emb1, const float* __restrict__ emb2,
                         bf16_t* __restrict__ x, int n, int N) {
  int idx = blockIdx.x * 256 + threadIdx.x;
  if (idx >= N * 128) return;
  int row = idx >> 7, ch = idx & 127;
  float v;
  if (row < n) v = emb1[xa[row * 2] * 128 + ch] + emb2[xa[row * 2 + 1] * 128 + ch];
  else v = teb[(size_t)(row - n) * 128 + ch];
  x[idx] = (bf16_t)v;
}

__global__ void k_hist(const int* __restrict__ eidx, int* __restrict__ cnt, int E) {
  int i = blockIdx.x * 256 + threadIdx.x;
  if (i < E) atomicAdd(&cnt[eidx[E + i]], 1);
}

__global__ void k_scan1(const int* __restrict__ cnt, int* __restrict__ part,
                        int* __restrict__ bsum, int n) {
  __shared__ int s[256];
  int i = blockIdx.x * 256 + threadIdx.x;
  int v = (i < n) ? cnt[i] : 0;
  s[threadIdx.x] = v;
  for (int off = 1; off < 256; off <<= 1) {
    __syncthreads();
    int t = (threadIdx.x >= off) ? s[threadIdx.x - off] : 0;
    __syncthreads();
    s[threadIdx.x] += t;
  }
  __syncthreads();
  if (i < n) part[i] = s[threadIdx.x] - v;
  if (threadIdx.x == 255) bsum[blockIdx.x] = s[255];
}

__global__ void k_scan2(int* bsum, int nb) {
  __shared__ int s[512];
  int v = ((int)threadIdx.x < nb) ? bsum[threadIdx.x] : 0;
  s[threadIdx.x] = v;
  for (int off = 1; off < 512; off <<= 1) {
    __syncthreads();
    int t = ((int)threadIdx.x >= off) ? s[threadIdx.x - off] : 0;
    __syncthreads();
    s[threadIdx.x] += t;
  }
  __syncthreads();
  if ((int)threadIdx.x < nb) bsum[threadIdx.x] = s[threadIdx.x] - v;
}

__global__ void k_scan3(int* __restrict__ rp, const int* __restrict__ bsum,
                        int* __restrict__ fill, int n, int E) {
  int i = blockIdx.x * 256 + threadIdx.x;
  if (i < n) {
    int v = rp[i] + bsum[i >> 8];
    rp[i] = v;
    fill[i] = v;
  }
  if (i == 0) rp[n] = E;
}

__global__ void k_scatter(const int* __restrict__ eidx, const int* __restrict__ eattr,
                          int* __restrict__ fill, int* __restrict__ pack, int E) {
  int i = blockIdx.x * 256 + threadIdx.x;
  if (i >= E) return;
  int s = eidx[i];
  int d = eidx[E + i];
  int comb = eattr[2 * i] * 3 + eattr[2 * i + 1];
  int p = atomicAdd(&fill[d], 1);
  pack[p] = s | (comb << 20);
}

// agg = segment_sum(norm(x)[src]+emb, dst) + norm(x) + self_emb ; norm fused (scsh),
// virtual edges analytic. bf16 in/out, f32 accumulate. One wave per node.
__global__ void k_agg(const bf16_t* __restrict__ y, const int* __restrict__ batch,
                      const int* __restrict__ rp, const int* __restrict__ pack,
                      const float* __restrict__ ec, const float* __restrict__ scsh,
                      bf16_t* __restrict__ agg, int n, int N, int npg) {
  int node = blockIdx.x * 4 + (threadIdx.x >> 6);
  if (node >= N) return;
  int c2 = (threadIdx.x & 63) * 2;
  const bool nm = (scsh != nullptr);
  float scx = 1.f, scy = 1.f, shx = 0.f, shy = 0.f;
  if (nm) {
    float2 s = *(const float2*)(scsh + c2); scx = s.x; scy = s.y;
    float2 t = *(const float2*)(scsh + 128 + c2); shx = t.x; shy = t.y;
  }
  #define LDV(row, vx, vy) { \
    bf16x2v _h = *(const bf16x2v*)(y + ((size_t)(row) << 7) + c2); \
    float _vx = (float)_h[0], _vy = (float)_h[1]; \
    if (nm) { _vx = fmaxf(fmaf(_vx, scx, shx), 0.f); _vy = fmaxf(fmaf(_vy, scy, shy), 0.f); } \
    vx = _vx; vy = _vy; }
  float2 self_e = *(const float2*)(ec + 12 * 128 + c2);  // e1[4]+e2[0]
  float2 virt_e = *(const float2*)(ec + 15 * 128 + c2);  // e1[5]+e2[0]
  float ax, ay;
  if (node < n) {
    int b = batch[node];
    float x0, y0, x1, y1;
    LDV(node, x0, y0);
    LDV(n + b, x1, y1);
    ax = x0 + x1 + self_e.x + virt_e.x;
    ay = y0 + y1 + self_e.y + virt_e.y;
    int beg = rp[node], end = rp[node + 1];
    for (int e = beg; e < end; ++e) {
      int p = pack[e];
      float vx, vy;
      LDV(p & 0xFFFFF, vx, vy);
      float2 em = *(const float2*)(ec + ((p >> 20) & 31) * 128 + c2);
      ax += vx + em.x;
      ay += vy + em.y;
    }
  } else {
    int b = node - n;
    float x0, y0;
    LDV(node, x0, y0);
    ax = x0 + self_e.x + (float)npg * virt_e.x;
    ay = y0 + self_e.y + (float)npg * virt_e.y;
    int base = b * npg;
    for (int k = 0; k < npg; ++k) {
      float vx, vy;
      LDV(base + k, vx, vy);
      ax += vx; ay += vy;
    }
  }
  #undef LDV
  bf16x2v o = { (bf16_t)ax, (bf16_t)ay };
  *(bf16x2v*)(agg + ((size_t)node << 7) + c2) = o;
}

// Fused MLP: y = relu(agg@W1+b1)@W2+b2, optional FiLM on rows<n, + batchnorm stats.
// Wave w owns cols [64w,64w+64) of GEMM1 and [32w,32w+32) of GEMM2, all 64 rows.
__launch_bounds__(256, 2)
__global__ void k_mlp(const bf16_t* __restrict__ agg, const bf16_t* __restrict__ W1T,
                      const bf16_t* __restrict__ W2T, const float* __restrict__ b1,
                      const float* __restrict__ b2, const float* __restrict__ gamma,
                      const float* __restrict__ beta, const int* __restrict__ batch,
                      bf16_t* __restrict__ y, float* __restrict__ gstats, int n, int N) {
  __shared__ __align__(16) char Hs[32768];   // [64][256] bf16, swizzled ^((r&15)<<4)
  __shared__ float sred[256];
  const int tid = threadIdx.x;
  const int m0 = blockIdx.x * 64;
  const int wave = tid >> 6, lane = tid & 63;
  const int lr = lane & 15, lk = lane >> 4;
  const int w64 = wave * 64, w32 = wave * 32;

  // preload GEMM1 B frags (16 x 16B = 64 VGPR)
  bf16x8 bb1[4][4];
  #pragma unroll
  for (int cf = 0; cf < 4; ++cf)
    #pragma unroll
    for (int kk = 0; kk < 4; ++kk)
      bb1[cf][kk] = *(const bf16x8*)(W1T + ((w64 + cf * 16 + lr) << 7) + kk * 32 + (lk << 3));

  int ar[4];
  #pragma unroll
  for (int rf = 0; rf < 4; ++rf) {
    int r = m0 + rf * 16 + lr;
    ar[rf] = r < N ? r : N - 1;
  }

  f32x4 acc1[4][4];
  f32x4 zero4 = {0.f, 0.f, 0.f, 0.f};
  #pragma unroll
  for (int rf = 0; rf < 4; ++rf)
    #pragma unroll
    for (int cf = 0; cf < 4; ++cf) acc1[rf][cf] = zero4;

  #pragma unroll
  for (int kk = 0; kk < 4; ++kk) {
    bf16x8 a[4];
    #pragma unroll
    for (int rf = 0; rf < 4; ++rf)
      a[rf] = *(const bf16x8*)(agg + ((size_t)ar[rf] << 7) + kk * 32 + (lk << 3));
    #pragma unroll
    for (int rf = 0; rf < 4; ++rf)
      #pragma unroll
      for (int cf = 0; cf < 4; ++cf)
        acc1[rf][cf] = __builtin_amdgcn_mfma_f32_16x16x32_bf16(a[rf], bb1[cf][kk], acc1[rf][cf], 0, 0, 0);
  }

  // preload GEMM2 B frags (overlaps with epilogue1 + barrier)
  bf16x8 bb2[2][8];
  #pragma unroll
  for (int cf = 0; cf < 2; ++cf)
    #pragma unroll
    for (int kk = 0; kk < 8; ++kk)
      bb2[cf][kk] = *(const bf16x8*)(W2T + ((w32 + cf * 16 + lr) << 8) + kk * 32 + (lk << 3));

  // epilogue1: bias + relu -> Hs (bf16, swizzled)
  #pragma unroll
  for (int rf = 0; rf < 4; ++rf)
    #pragma unroll
    for (int cf = 0; cf < 4; ++cf) {
      int col = w64 + cf * 16 + lr;
      float bias = b1[col];
      #pragma unroll
      for (int j = 0; j < 4; ++j) {
        int r = rf * 16 + lk * 4 + j;
        float h = acc1[rf][cf][j] + bias;
        h = h > 0.f ? h : 0.f;
        int byte = (r << 9) + col * 2;
        byte ^= (r & 15) << 4;
        *(bf16_t*)(Hs + byte) = (bf16_t)h;
      }
    }
  __syncthreads();

  f32x4 acc2[4][2];
  #pragma unroll
  for (int rf = 0; rf < 4; ++rf)
    #pragma unroll
    for (int cf = 0; cf < 2; ++cf) acc2[rf][cf] = zero4;

  #pragma unroll
  for (int kk = 0; kk < 8; ++kk) {
    bf16x8 a2[4];
    #pragma unroll
    for (int rf = 0; rf < 4; ++rf) {
      int row = rf * 16 + lr;
      int byte = (row << 9) + kk * 64 + (lk << 4);
      byte ^= (row & 15) << 4;
      a2[rf] = *(const bf16x8*)(Hs + byte);
    }
    #pragma unroll
    for (int rf = 0; rf < 4; ++rf)
      #pragma unroll
      for (int cf = 0; cf < 2; ++cf)
        acc2[rf][cf] = __builtin_amdgcn_mfma_f32_16x16x32_bf16(a2[rf], bb2[cf][kk], acc2[rf][cf], 0, 0, 0);
  }

  int gb[4][4];
  #pragma unroll
  for (int rf = 0; rf < 4; ++rf)
    #pragma unroll
    for (int j = 0; j < 4; ++j) {
      int row = m0 + rf * 16 + lk * 4 + j;
      gb[rf][j] = (gamma != nullptr && row < n) ? batch[row] : -1;
    }

  #pragma unroll
  for (int cf = 0; cf < 2; ++cf) {
    int col = w32 + cf * 16 + lr;
    float bias = b2[col];
    float s = 0.f, q = 0.f;
    #pragma unroll
    for (int rf = 0; rf < 4; ++rf)
      #pragma unroll
      for (int j = 0; j < 4; ++j) {
        int row = m0 + rf * 16 + lk * 4 + j;
        if (row < N) {
          float v = acc2[rf][cf][j] + bias;
          if (gb[rf][j] >= 0)
            v = gamma[(size_t)gb[rf][j] * 128 + col] * v + beta[(size_t)gb[rf][j] * 128 + col];
          y[(size_t)row * 128 + col] = (bf16_t)v;
          s += v; q += v * v;
        }
      }
    s += __shfl_xor(s, 16, 64); s += __shfl_xor(s, 32, 64);
    q += __shfl_xor(q, 16, 64); q += __shfl_xor(q, 32, 64);
    if (lane < 16) { sred[col] = s; sred[128 + col] = q; }  // cols wave-partitioned
  }
  __syncthreads();
  atomicAdd(&gstats[((blockIdx.x & 15) << 8) + tid], sred[tid]);
}

// sums 16 partial copies; writes sc at [4096..4223], sh at [4224..4351]; re-zeros partials
__global__ void k_finalize(float* st, const float* __restrict__ bnw,
                           const float* __restrict__ bnb, float invN) {
  int ch = threadIdx.x;
  float s = 0.f, q = 0.f;
  #pragma unroll
  for (int c = 0; c < 16; ++c) { s += st[c * 256 + ch]; q += st[c * 256 + 128 + ch]; }
  __syncthreads();
  #pragma unroll
  for (int z = 0; z < 32; ++z) st[ch * 32 + z] = 0.f;
  float mean = s * invN;
  float var = fmaxf(q * invN - mean * mean, 0.f);
  float inv = rsqrtf(var + EPSV);
  float sc = inv * bnw[ch];
  st[4096 + ch] = sc;
  st[4224 + ch] = bnb[ch] - mean * sc;
}

// final normalize (no relu) of first n rows -> d_out (f32); 8 elems/thread
__global__ void k_norm(const bf16_t* __restrict__ yin, const float* __restrict__ scsh,
                       float* __restrict__ out, int total8) {
  int i = blockIdx.x * 256 + threadIdx.x;
  if (i >= total8) return;
  int ch8 = i & 15;
  bf16x8 v = ((const bf16x8*)yin)[i];
  float4 sc0 = ((const float4*)scsh)[ch8 * 2];
  float4 sc1 = ((const float4*)scsh)[ch8 * 2 + 1];
  float4 sh0 = ((const float4*)(scsh + 128))[ch8 * 2];
  float4 sh1 = ((const float4*)(scsh + 128))[ch8 * 2 + 1];
  float4 r0, r1;
  r0.x = (float)v[0] * sc0.x + sh0.x;
  r0.y = (float)v[1] * sc0.y + sh0.y;
  r0.z = (float)v[2] * sc0.z + sh0.z;
  r0.w = (float)v[3] * sc0.w + sh0.w;
  r1.x = (float)v[4] * sc1.x + sh1.x;
  r1.y = (float)v[5] * sc1.y + sh1.y;
  r1.z = (float)v[6] * sc1.z + sh1.z;
  r1.w = (float)v[7] * sc1.w + sh1.w;
  ((float4*)out)[i * 2] = r0;
  ((float4*)out)[i * 2 + 1] = r1;
}

extern "C" void kernel_launch(void* const* d_in, const int* in_sizes, int n_in,
                              void* d_out, int out_size, void* d_ws, size_t ws_size,
                              hipStream_t stream) {
  const int*   x_atoms    = (const int*)d_in[0];
  const int*   edge_index = (const int*)d_in[1];
  const int*   edge_attr  = (const int*)d_in[2];
  const int*   batch      = (const int*)d_in[3];
  const float* task_embs  = (const float*)d_in[6];
  const float* teb        = (const float*)d_in[7];
  const float* emb1       = (const float*)d_in[8];
  const float* emb2       = (const float*)d_in[9];
  const float* edge_e1    = (const float*)d_in[10];
  const float* edge_e2    = (const float*)d_in[11];
  const float* W1         = (const float*)d_in[12];
  const float* b1         = (const float*)d_in[13];
  const float* W2         = (const float*)d_in[14];
  const float* b2         = (const float*)d_in[15];
  const float* bnw        = (const float*)d_in[16];
  const float* bnb        = (const float*)d_in[17];
  const float* fWg        = (const float*)d_in[18];
  const float* fbg        = (const float*)d_in[19];
  const float* fWb        = (const float*)d_in[20];
  const float* fbb        = (const float*)d_in[21];

  const int n   = in_sizes[0] / 2;
  const int E   = in_sizes[1] / 2;
  const int g   = in_sizes[6] / 128;
  const int N   = n + g;
  const int npg = n / g;
  const int L   = in_sizes[12] / 32768;

  char* ws = (char*)d_ws;
  size_t off = 0;
  auto alloc = [&](size_t bytes) { size_t o = off; off += (bytes + 255) & ~(size_t)255; return o; };
  bf16_t* xbuf   = (bf16_t*)(ws + alloc((size_t)N * 128 * 2));
  bf16_t* aggb   = (bf16_t*)(ws + alloc((size_t)N * 128 * 2));
  float*  gbuf   = (float*)(ws + alloc((size_t)4 * g * 128 * 4));
  bf16_t* W1Tb   = (bf16_t*)(ws + alloc((size_t)L * 32768 * 2));
  bf16_t* W2Tb   = (bf16_t*)(ws + alloc((size_t)L * 32768 * 2));
  bf16_t* fWTb   = (bf16_t*)(ws + alloc((size_t)4 * 16384 * 2));
  bf16_t* tebuf  = (bf16_t*)(ws + alloc((size_t)g * 128 * 2));
  float*  ecomb  = (float*)(ws + alloc((size_t)L * 18 * 128 * 4));
  float*  gstats = (float*)(ws + alloc((size_t)(4096 + 256) * 4));
  int*    row_ptr= (int*)(ws + alloc((size_t)(n + 1) * 4));
  int*    fill   = (int*)(ws + alloc((size_t)n * 4));
  int*    epack  = (int*)(ws + alloc((size_t)E * 4));
  int*    bsum   = (int*)(ws + alloc(512 * 4));
  (void)ws_size; (void)n_in; (void)out_size;

  // one-time-per-launch precompute
  k_prep_weights<<<(L * 32768 + 255) / 256, 256, 0, stream>>>(W1, W2, W1Tb, W2Tb, L * 32768);
  k_prep_film<<<(4 * 16384 + 255) / 256, 256, 0, stream>>>(fWg, fWb, fWTb);
  k_prep_te<<<(g * 128 + 255) / 256, 256, 0, stream>>>(task_embs, tebuf, g * 128);
  k_init_x<<<(N * 128 + 255) / 256, 256, 0, stream>>>(x_atoms, teb, emb1, emb2, xbuf, n, N);
  k_ecomb<<<(L * 18 * 128 + 255) / 256, 256, 0, stream>>>(edge_e1, edge_e2, ecomb, L * 18 * 128);
  k_film<<<(g / 64) * 4, 256, 0, stream>>>(tebuf, fWTb, fbg, fbb, gbuf, g);

  // CSR build (by dst) for real edges
  const int nb = (n + 255) / 256;
  k_zeroi<<<nb, 256, 0, stream>>>(fill, n);
  k_hist<<<(E + 255) / 256, 256, 0, stream>>>(edge_index, fill, E);
  k_scan1<<<nb, 256, 0, stream>>>(fill, row_ptr, bsum, n);
  k_scan2<<<1, 512, 0, stream>>>(bsum, nb);
  k_scan3<<<nb, 256, 0, stream>>>(row_ptr, bsum, fill, n, E);
  k_scatter<<<(E + 255) / 256, 256, 0, stream>>>(edge_index, edge_attr, fill, epack, E);

  k_zerof<<<16, 256, 0, stream>>>(gstats, 4096);
  for (int l = 0; l < 4; ++l) {
    const float* scsh = (l == 0) ? nullptr : (gstats + 4096);
    k_agg<<<(N + 3) / 4, 256, 0, stream>>>(xbuf, batch, row_ptr, epack,
        ecomb + (size_t)l * 18 * 128, scsh, aggb, n, N, npg);
    const float* gm = nullptr; const float* bt = nullptr;
    if (l == 1) { gm = gbuf;                       bt = gbuf + (size_t)g * 128; }
    if (l == 3) { gm = gbuf + (size_t)2 * g * 128; bt = gbuf + (size_t)3 * g * 128; }
    k_mlp<<<(N + 63) / 64, 256, 0, stream>>>(aggb, W1Tb + (size_t)l * 32768,
        W2Tb + (size_t)l * 32768, b1 + l * 256, b2 + l * 128, gm, bt, batch,
        xbuf, gstats, n, N);
    k_finalize<<<1, 128, 0, stream>>>(gstats, bnw + l * 128, bnb + l * 128, 1.0f / (float)N);
  }
  k_norm<<<(n * 16 + 255) / 256, 256, 0, stream>>>(xbuf, gstats + 4096, (float*)d_out, n * 16);
}